// Round 3
// baseline (1060.665 us; speedup 1.0000x reference)
//
#include <hip/hip_runtime.h>
#include <math.h>

#define DM   1024
#define NH   16
#define HD   64
#define BATCH 2
#define SEQ  2048
#define MR   (BATCH*SEQ)   // 4096 rows

typedef __attribute__((ext_vector_type(8))) short bf16x8;
typedef __attribute__((ext_vector_type(4))) float f32x4;

__device__ __forceinline__ unsigned short f2bf(float x) {
    unsigned u = __builtin_bit_cast(unsigned, x);
    u = (u + 0x7FFFu + ((u >> 16) & 1u)) >> 16;
    return (unsigned short)u;
}
__device__ __forceinline__ float bf2f(unsigned short s) {
    unsigned u = ((unsigned)s) << 16;
    return __builtin_bit_cast(float, u);
}

// ---------------------------------------------------------------------------
// fp32 -> bf16 split (hi + lo) / single conversions
// ---------------------------------------------------------------------------
__global__ __launch_bounds__(256) void convert_split(
    const float* __restrict__ src, unsigned short* __restrict__ hi,
    unsigned short* __restrict__ lo, int n4)
{
    int i = blockIdx.x * 256 + threadIdx.x;
    if (i >= n4) return;
    float4 v = ((const float4*)src)[i];
    float f[4] = {v.x, v.y, v.z, v.w};
    unsigned short h[4], l[4];
#pragma unroll
    for (int k = 0; k < 4; ++k) {
        h[k] = f2bf(f[k]);
        l[k] = f2bf(f[k] - bf2f(h[k]));
    }
    ((ushort4*)hi)[i] = make_ushort4(h[0], h[1], h[2], h[3]);
    ((ushort4*)lo)[i] = make_ushort4(l[0], l[1], l[2], l[3]);
}

__global__ __launch_bounds__(256) void convert_single(
    const float* __restrict__ src, unsigned short* __restrict__ dst, int n4)
{
    int i = blockIdx.x * 256 + threadIdx.x;
    if (i >= n4) return;
    float4 v = ((const float4*)src)[i];
    ((ushort4*)dst)[i] = make_ushort4(f2bf(v.x), f2bf(v.y), f2bf(v.z), f2bf(v.w));
}

// ---------------------------------------------------------------------------
// MFMA projection GEMM: C[M,1024] = A[M,1024] @ W[1024,1024]^T + bias
// (unchanged from R2 — A pre-converted bf16, staging is pure uint4 copy)
// ---------------------------------------------------------------------------
template<int MODE>
__global__ __launch_bounds__(256) void proj_gemm(
    const unsigned short* __restrict__ Ahi, const unsigned short* __restrict__ Alo,
    const unsigned short* __restrict__ Bhi, const unsigned short* __restrict__ Blo,
    const float* __restrict__ bias,
    void* __restrict__ out0, unsigned short* __restrict__ out1)
{
    __shared__ __align__(16) short As[2][64][40];    // 32 k + 8 pad
    __shared__ __align__(16) short Bs[2][128][40];

    const int tid  = threadIdx.x;
    const int wave = tid >> 6, lane = tid & 63;
    const int quad = lane >> 4, lr = lane & 15;
    const int wy = wave >> 1, wx = wave & 1;
    const int m0 = blockIdx.x * 64, n0 = blockIdx.y * 128;

    f32x4 acc[2][4];
#pragma unroll
    for (int i = 0; i < 2; ++i)
#pragma unroll
        for (int j = 0; j < 4; ++j) acc[i][j] = (f32x4){0.f, 0.f, 0.f, 0.f};

    const int arow = tid >> 2, aseg = (tid & 3) * 8;   // A: 64 rows x 4 segs of 8
    const int brow = tid >> 1, bseg = (tid & 1) * 16;  // B: 128 rows x 2 segs of 16

    for (int k0 = 0; k0 < DM; k0 += 32) {
        __syncthreads();
        {
            const size_t ao = (size_t)(m0 + arow) * DM + k0 + aseg;
            *(uint4*)&As[0][arow][aseg] = *(const uint4*)&Ahi[ao];
            if (MODE == 0)
                *(uint4*)&As[1][arow][aseg] = *(const uint4*)&Alo[ao];
        }
        {
            const size_t bo = (size_t)(n0 + brow) * DM + k0 + bseg;
            *(uint4*)&Bs[0][brow][bseg]     = *(const uint4*)&Bhi[bo];
            *(uint4*)&Bs[0][brow][bseg + 8] = *(const uint4*)&Bhi[bo + 8];
            if (MODE == 0) {
                *(uint4*)&Bs[1][brow][bseg]     = *(const uint4*)&Blo[bo];
                *(uint4*)&Bs[1][brow][bseg + 8] = *(const uint4*)&Blo[bo + 8];
            }
        }
        __syncthreads();
        bf16x8 ah[2], al[2], bh[4], bl[4];
#pragma unroll
        for (int i = 0; i < 2; ++i) {
            ah[i] = *(const bf16x8*)&As[0][wy * 32 + i * 16 + lr][quad * 8];
            if (MODE == 0) al[i] = *(const bf16x8*)&As[1][wy * 32 + i * 16 + lr][quad * 8];
        }
#pragma unroll
        for (int j = 0; j < 4; ++j) {
            bh[j] = *(const bf16x8*)&Bs[0][wx * 64 + j * 16 + lr][quad * 8];
            if (MODE == 0) bl[j] = *(const bf16x8*)&Bs[1][wx * 64 + j * 16 + lr][quad * 8];
        }
#pragma unroll
        for (int i = 0; i < 2; ++i)
#pragma unroll
            for (int j = 0; j < 4; ++j) {
                acc[i][j] = __builtin_amdgcn_mfma_f32_16x16x32_bf16(ah[i], bh[j], acc[i][j], 0, 0, 0);
                if (MODE == 0) {
                    acc[i][j] = __builtin_amdgcn_mfma_f32_16x16x32_bf16(ah[i], bl[j], acc[i][j], 0, 0, 0);
                    acc[i][j] = __builtin_amdgcn_mfma_f32_16x16x32_bf16(al[i], bh[j], acc[i][j], 0, 0, 0);
                }
            }
    }

    float bj[4];
#pragma unroll
    for (int j = 0; j < 4; ++j) bj[j] = bias[n0 + wx * 64 + j * 16 + lr];

    if (MODE == 0) {
        unsigned short* Ohi = (unsigned short*)out0;
#pragma unroll
        for (int i = 0; i < 2; ++i) {
#pragma unroll
            for (int r = 0; r < 4; ++r) {
                float x[4];
#pragma unroll
                for (int j = 0; j < 4; ++j) x[j] = acc[i][j][r] + bj[j];
                float t = x[0] + x[1] + x[2] + x[3];
                t += __shfl_xor(t, 1, 16);
                t += __shfl_xor(t, 2, 16);
                t += __shfl_xor(t, 4, 16);
                t += __shfl_xor(t, 8, 16);
                const float mean = t * (1.0f / 64.0f);
                float ss = 0.f;
#pragma unroll
                for (int j = 0; j < 4; ++j) { x[j] -= mean; ss += x[j] * x[j]; }
                ss += __shfl_xor(ss, 1, 16);
                ss += __shfl_xor(ss, 2, 16);
                ss += __shfl_xor(ss, 4, 16);
                ss += __shfl_xor(ss, 8, 16);
                const float inv = 1.0f / fmaxf(sqrtf(ss), 1e-12f);
                const int row = m0 + wy * 32 + i * 16 + quad * 4 + r;
#pragma unroll
                for (int j = 0; j < 4; ++j) {
                    const float y = x[j] * inv;
                    const unsigned short hh = f2bf(y);
                    const unsigned short ll = f2bf(y - bf2f(hh));
                    const size_t o = (size_t)row * DM + n0 + wx * 64 + j * 16 + lr;
                    Ohi[o]  = hh;
                    out1[o] = ll;
                }
            }
        }
    } else if (MODE == 1) {
        unsigned short* Vg = (unsigned short*)out0;
        const int h = (n0 + wx * 64) >> 6;
#pragma unroll
        for (int i = 0; i < 2; ++i) {
            const int grow = m0 + wy * 32 + i * 16 + quad * 4;
            const int bb = grow >> 11, ss = grow & (SEQ - 1);
#pragma unroll
            for (int j = 0; j < 4; ++j) {
                const int d = j * 16 + lr;
                ushort4 pk;
                pk.x = f2bf(acc[i][j][0] + bj[j]);
                pk.y = f2bf(acc[i][j][1] + bj[j]);
                pk.z = f2bf(acc[i][j][2] + bj[j]);
                pk.w = f2bf(acc[i][j][3] + bj[j]);
                *(ushort4*)&Vg[((size_t)(bb * NH + h) * HD + d) * SEQ + ss] = pk;
            }
        }
    } else {
        float* O = (float*)out0;
#pragma unroll
        for (int i = 0; i < 2; ++i)
#pragma unroll
            for (int j = 0; j < 4; ++j)
#pragma unroll
                for (int r = 0; r < 4; ++r)
                    O[(size_t)(m0 + wy * 32 + i * 16 + quad * 4 + r) * DM +
                      n0 + wx * 64 + j * 16 + lr] = acc[i][j][r] + bj[j];
    }
}

// ---------------------------------------------------------------------------
// Fused attention, SINGLE-PASS, MFMA.
// Scores are bounded (|scale*q.k| <= 12, Q/K row-normalized) -> no online max.
// Stores UNNORMALIZED e = exp2(s*s2 + c2) to attn; accumulates PV with e;
// scales acc_o by rinv at the end (linearity); writes rowinv for a separate
// streaming rescale pass over attn.
// T14: next-tile K/V/mask prefetched into regs before compute; raw s_barrier
// with lgkmcnt(0)-only waits keeps the prefetch loads in flight (no vmcnt(0)
// drain). T5: setprio(1) around MFMA clusters.
// ---------------------------------------------------------------------------
__global__ __launch_bounds__(256) void attn_fused(
    const unsigned short* __restrict__ Qhi, const unsigned short* __restrict__ Qlo,
    const unsigned short* __restrict__ Khi, const unsigned short* __restrict__ Klo,
    const unsigned short* __restrict__ Vg,  const int* __restrict__ mask,
    const float* __restrict__ scale_p,
    float* __restrict__ attn, unsigned short* __restrict__ ctxb,
    float* __restrict__ rowinv_g)
{
    __shared__ __align__(16) short KHs[64][72];
    __shared__ __align__(16) short KLs[64][72];
    __shared__ __align__(16) short Vs[64][72];
    __shared__ __align__(16) short Ps[64][68];   // stride 68: no inter-quad bank clash
    __shared__ float mkf[64];

    const int tid = threadIdx.x;
    const int w = tid >> 6, lane = tid & 63;
    const int quad = lane >> 4, lr = lane & 15;

    // XCD-aware bijective swizzle: 1024 = 8 XCDs * 128 contiguous blocks
    const int lin = blockIdx.x;
    const int swz = (lin & 7) * 128 + (lin >> 3);
    const int b  = swz >> 9;
    const int h  = (swz >> 5) & 15;
    const int q0 = (swz & 31) * 64;

    const float scl = scale_p[0];
    const float s2 = scl * 1.44269504089f;
    const float c2 = -12.0f * 1.44269504089f;

    const int r0 = tid >> 3,        c0 = (tid & 7) * 8;
    const int r1 = (tid >> 3) + 32, c1 = (tid & 7) * 8;

    // ---- stage Q (KHs/KLs as temp), grab register fragments ----
    {
        const size_t base = ((size_t)(b * SEQ + q0)) * DM + h * HD;
        *(uint4*)&KHs[r0][c0] = *(const uint4*)&Qhi[base + (size_t)r0 * DM + c0];
        *(uint4*)&KHs[r1][c1] = *(const uint4*)&Qhi[base + (size_t)r1 * DM + c1];
        *(uint4*)&KLs[r0][c0] = *(const uint4*)&Qlo[base + (size_t)r0 * DM + c0];
        *(uint4*)&KLs[r1][c1] = *(const uint4*)&Qlo[base + (size_t)r1 * DM + c1];
    }
    __syncthreads();
    bf16x8 qh[2], ql[2];
#pragma unroll
    for (int kc = 0; kc < 2; ++kc) {
        qh[kc] = *(const bf16x8*)&KHs[w * 16 + lr][kc * 32 + quad * 8];
        ql[kc] = *(const bf16x8*)&KLs[w * 16 + lr][kc * 32 + quad * 8];
    }

    float rs[4] = {0.f, 0.f, 0.f, 0.f};
    f32x4 acc_o[4];
#pragma unroll
    for (int dt = 0; dt < 4; ++dt) acc_o[dt] = (f32x4){0.f, 0.f, 0.f, 0.f};

    // prefetch registers for tile kt
    uint4 pKH0, pKH1, pKL0, pKL1, pV0, pV1;
    int pmk = 0;

    auto load_tile = [&](int kt) {
        const int kk = kt * 64;
        const size_t kb = ((size_t)(b * SEQ + kk)) * DM + h * HD;
        const size_t vb = ((size_t)((b * NH + h) * HD)) * SEQ + kk;
        pKH0 = *(const uint4*)&Khi[kb + (size_t)r0 * DM + c0];
        pKH1 = *(const uint4*)&Khi[kb + (size_t)r1 * DM + c1];
        pKL0 = *(const uint4*)&Klo[kb + (size_t)r0 * DM + c0];
        pKL1 = *(const uint4*)&Klo[kb + (size_t)r1 * DM + c1];
        pV0  = *(const uint4*)&Vg[vb + (size_t)r0 * SEQ + c0];
        pV1  = *(const uint4*)&Vg[vb + (size_t)r1 * SEQ + c1];
        if (tid < 64) pmk = mask[b * SEQ + kk + tid];
    };

    load_tile(0);

    for (int kt = 0; kt < SEQ / 64; ++kt) {
        // barrier 1: all LDS reads of previous tile done (lgkm only, vm stays)
        asm volatile("s_waitcnt lgkmcnt(0)" ::: "memory");
        __builtin_amdgcn_s_barrier();
        __builtin_amdgcn_sched_barrier(0);

        // write staged tile to LDS (compiler waits vmcnt for pf regs here)
        *(uint4*)&KHs[r0][c0] = pKH0;
        *(uint4*)&KHs[r1][c1] = pKH1;
        *(uint4*)&KLs[r0][c0] = pKL0;
        *(uint4*)&KLs[r1][c1] = pKL1;
        *(uint4*)&Vs[r0][c0]  = pV0;
        *(uint4*)&Vs[r1][c1]  = pV1;
        if (tid < 64) mkf[tid] = pmk ? c2 : -3.0e38f;

        // issue next tile's global loads (fly during compute below)
        if (kt + 1 < SEQ / 64) load_tile(kt + 1);

        // barrier 2: LDS tile visible (lgkm only)
        asm volatile("s_waitcnt lgkmcnt(0)" ::: "memory");
        __builtin_amdgcn_s_barrier();
        __builtin_amdgcn_sched_barrier(0);

        const int kk = kt * 64;
#pragma unroll
        for (int j = 0; j < 4; ++j) {
            bf16x8 bh0 = *(const bf16x8*)&KHs[j * 16 + lr][quad * 8];
            bf16x8 bh1 = *(const bf16x8*)&KHs[j * 16 + lr][32 + quad * 8];
            bf16x8 bl0 = *(const bf16x8*)&KLs[j * 16 + lr][quad * 8];
            bf16x8 bl1 = *(const bf16x8*)&KLs[j * 16 + lr][32 + quad * 8];
            f32x4 sa = (f32x4){0.f, 0.f, 0.f, 0.f};
            __builtin_amdgcn_s_setprio(1);
            sa = __builtin_amdgcn_mfma_f32_16x16x32_bf16(qh[0], bh0, sa, 0, 0, 0);
            sa = __builtin_amdgcn_mfma_f32_16x16x32_bf16(ql[0], bh0, sa, 0, 0, 0);
            sa = __builtin_amdgcn_mfma_f32_16x16x32_bf16(qh[0], bl0, sa, 0, 0, 0);
            sa = __builtin_amdgcn_mfma_f32_16x16x32_bf16(qh[1], bh1, sa, 0, 0, 0);
            sa = __builtin_amdgcn_mfma_f32_16x16x32_bf16(ql[1], bh1, sa, 0, 0, 0);
            sa = __builtin_amdgcn_mfma_f32_16x16x32_bf16(qh[1], bl1, sa, 0, 0, 0);
            __builtin_amdgcn_s_setprio(0);
            const float mo = mkf[j * 16 + lr];
#pragma unroll
            for (int r = 0; r < 4; ++r) {
                const float e = exp2f(fmaf(sa[r], s2, mo));
                rs[r] += e;
                const int qrow = q0 + w * 16 + quad * 4 + r;
                attn[((size_t)(b * NH + h) * SEQ + qrow) * SEQ + kk + j * 16 + lr] = e;
                Ps[w * 16 + quad * 4 + r][j * 16 + lr] = (short)f2bf(e);
            }
        }
        // PV: wave reads only its own Ps rows (written above) -> no barrier
        bf16x8 pa0 = *(const bf16x8*)&Ps[w * 16 + lr][quad * 8];
        bf16x8 pa1 = *(const bf16x8*)&Ps[w * 16 + lr][32 + quad * 8];
        __builtin_amdgcn_s_setprio(1);
#pragma unroll
        for (int dt = 0; dt < 4; ++dt) {
            bf16x8 bv0 = *(const bf16x8*)&Vs[dt * 16 + lr][quad * 8];
            bf16x8 bv1 = *(const bf16x8*)&Vs[dt * 16 + lr][32 + quad * 8];
            acc_o[dt] = __builtin_amdgcn_mfma_f32_16x16x32_bf16(pa0, bv0, acc_o[dt], 0, 0, 0);
            acc_o[dt] = __builtin_amdgcn_mfma_f32_16x16x32_bf16(pa1, bv1, acc_o[dt], 0, 0, 0);
        }
        __builtin_amdgcn_s_setprio(0);
    }

    // ---- row-sum reduce -> rinv; store rowinv; scale acc_o ----
    float rinv[4];
#pragma unroll
    for (int r = 0; r < 4; ++r) {
        float t = rs[r];
        t += __shfl_xor(t, 1, 16);
        t += __shfl_xor(t, 2, 16);
        t += __shfl_xor(t, 4, 16);
        t += __shfl_xor(t, 8, 16);
        rinv[r] = 1.0f / fmaxf(t, 1e-30f);
    }
    if (lr == 0) {
        const size_t base = (size_t)(b * NH + h) * SEQ + q0 + w * 16 + quad * 4;
#pragma unroll
        for (int r = 0; r < 4; ++r) rowinv_g[base + r] = rinv[r];
    }
#pragma unroll
    for (int dt = 0; dt < 4; ++dt)
#pragma unroll
        for (int r = 0; r < 4; ++r) acc_o[dt][r] *= rinv[r];

    // ---- ctx out (bf16, row-major [B,S,D]) ----
#pragma unroll
    for (int dt = 0; dt < 4; ++dt)
#pragma unroll
        for (int r = 0; r < 4; ++r)
            ctxb[((size_t)(b * SEQ + q0 + w * 16 + quad * 4 + r)) * DM +
                 h * HD + dt * 16 + lr] = (unsigned short)f2bf(acc_o[dt][r]);
}

// ---------------------------------------------------------------------------
// Streaming rescale: attn[i] *= rowinv[row]. Pure BW kernel.
// ---------------------------------------------------------------------------
__global__ __launch_bounds__(256) void rescale_attn(
    float* __restrict__ attn, const float* __restrict__ rowinv)
{
    const size_t N4 = (size_t)BATCH * NH * SEQ * (SEQ / 4);
    size_t i = (size_t)blockIdx.x * 256 + threadIdx.x;
    const size_t stride = (size_t)gridDim.x * 256;
    for (; i < N4; i += stride) {
        float4 v = ((float4*)attn)[i];
        const float s = rowinv[i >> 9];   // 512 float4 per row
        v.x *= s; v.y *= s; v.z *= s; v.w *= s;
        ((float4*)attn)[i] = v;
    }
}

// ---------------------------------------------------------------------------
extern "C" void kernel_launch(void* const* d_in, const int* in_sizes, int n_in,
                              void* d_out, int out_size, void* d_ws, size_t ws_size,
                              hipStream_t stream)
{
    const float* query = (const float*)d_in[0];
    const float* key   = (const float*)d_in[1];
    const float* value = (const float*)d_in[2];
    const int*   mask  = (const int*)d_in[3];
    const float* Wq = (const float*)d_in[4];
    const float* bq = (const float*)d_in[5];
    const float* Wk = (const float*)d_in[6];
    const float* bk = (const float*)d_in[7];
    const float* Wv = (const float*)d_in[8];
    const float* bv = (const float*)d_in[9];
    const float* Wo = (const float*)d_in[10];
    const float* bo = (const float*)d_in[11];
    const float* scale = (const float*)d_in[12];

    float* out_ctx  = (float*)d_out;                 // [B,S,DM]
    float* out_attn = out_ctx + (size_t)MR * DM;     // [B,NH,S,S]

    const size_t WSZ = (size_t)DM * DM;   // 1M elems
    const size_t TSZ = (size_t)MR * DM;   // 4M elems
    unsigned short* p = (unsigned short*)d_ws;
    unsigned short* Wq_hi = p; p += WSZ;
    unsigned short* Wq_lo = p; p += WSZ;
    unsigned short* Wk_hi = p; p += WSZ;
    unsigned short* Wk_lo = p; p += WSZ;
    unsigned short* Wv_b  = p; p += WSZ;
    unsigned short* Wo_b  = p; p += WSZ;
    unsigned short* Qn_hi = p; p += TSZ;
    unsigned short* Qn_lo = p; p += TSZ;
    unsigned short* Kn_hi = p; p += TSZ;
    unsigned short* Kn_lo = p; p += TSZ;
    unsigned short* Vg    = p; p += TSZ;
    // ctxb aliases Wq_hi..Wk_lo (4*WSZ == TSZ elems), dead after Q/K proj
    unsigned short* ctxb  = Wq_hi;
    // Activation pre-split scratch lives in the (not yet written) attn output
    unsigned short* Ahi = (unsigned short*)out_attn;
    unsigned short* Alo = Ahi + TSZ;
    // rowinv (64K floats) lives in out_ctx, overwritten later by proj_gemm<2>
    float* rowinv = out_ctx;

    convert_split <<<1024, 256, 0, stream>>>(Wq, Wq_hi, Wq_lo, 262144);
    convert_split <<<1024, 256, 0, stream>>>(Wk, Wk_hi, Wk_lo, 262144);
    convert_single<<<1024, 256, 0, stream>>>(Wv, Wv_b, 262144);
    convert_single<<<1024, 256, 0, stream>>>(Wo, Wo_b, 262144);

    dim3 gg(MR / 64, DM / 128);

    convert_split <<<4096, 256, 0, stream>>>(query, Ahi, Alo, (int)(TSZ / 4));
    proj_gemm<0><<<gg, 256, 0, stream>>>(Ahi, Alo, Wq_hi, Wq_lo, bq, Qn_hi, Qn_lo);
    convert_split <<<4096, 256, 0, stream>>>(key, Ahi, Alo, (int)(TSZ / 4));
    proj_gemm<0><<<gg, 256, 0, stream>>>(Ahi, Alo, Wk_hi, Wk_lo, bk, Kn_hi, Kn_lo);
    convert_single<<<4096, 256, 0, stream>>>(value, Ahi, (int)(TSZ / 4));
    proj_gemm<1><<<gg, 256, 0, stream>>>(Ahi, nullptr, Wv_b, nullptr, bv, Vg, nullptr);

    attn_fused<<<dim3(SEQ / 64 * NH * BATCH), 256, 0, stream>>>(
        Qn_hi, Qn_lo, Kn_hi, Kn_lo, Vg, mask, scale, out_attn, ctxb, rowinv);

    rescale_attn<<<4096, 256, 0, stream>>>(out_attn, rowinv);

    proj_gemm<2><<<gg, 256, 0, stream>>>(ctxb, nullptr, Wo_b, nullptr, bo, out_ctx, nullptr);
}

// Round 7
// 899.537 us; speedup vs baseline: 1.1791x; 1.1791x over previous
//
#include <hip/hip_runtime.h>
#include <math.h>

#define DM   1024
#define NH   16
#define HD   64
#define BATCH 2
#define SEQ  2048
#define MR   (BATCH*SEQ)   // 4096 rows

typedef __attribute__((ext_vector_type(8))) short bf16x8;
typedef __attribute__((ext_vector_type(4))) float f32x4;

__device__ __forceinline__ unsigned short f2bf(float x) {
    unsigned u = __builtin_bit_cast(unsigned, x);
    u = (u + 0x7FFFu + ((u >> 16) & 1u)) >> 16;
    return (unsigned short)u;
}
__device__ __forceinline__ float bf2f(unsigned short s) {
    unsigned u = ((unsigned)s) << 16;
    return __builtin_bit_cast(float, u);
}

// ---------------------------------------------------------------------------
// fp32 -> bf16 split (hi + lo) / single conversions
// ---------------------------------------------------------------------------
__global__ __launch_bounds__(256) void convert_split(
    const float* __restrict__ src, unsigned short* __restrict__ hi,
    unsigned short* __restrict__ lo, int n4)
{
    int i = blockIdx.x * 256 + threadIdx.x;
    if (i >= n4) return;
    float4 v = ((const float4*)src)[i];
    float f[4] = {v.x, v.y, v.z, v.w};
    unsigned short h[4], l[4];
#pragma unroll
    for (int k = 0; k < 4; ++k) {
        h[k] = f2bf(f[k]);
        l[k] = f2bf(f[k] - bf2f(h[k]));
    }
    ((ushort4*)hi)[i] = make_ushort4(h[0], h[1], h[2], h[3]);
    ((ushort4*)lo)[i] = make_ushort4(l[0], l[1], l[2], l[3]);
}

__global__ __launch_bounds__(256) void convert_single(
    const float* __restrict__ src, unsigned short* __restrict__ dst, int n4)
{
    int i = blockIdx.x * 256 + threadIdx.x;
    if (i >= n4) return;
    float4 v = ((const float4*)src)[i];
    ((ushort4*)dst)[i] = make_ushort4(f2bf(v.x), f2bf(v.y), f2bf(v.z), f2bf(v.w));
}

// ---------------------------------------------------------------------------
// MFMA projection GEMM: C[M,1024] = A[M,1024] @ W[1024,1024]^T + bias
// (unchanged from R2 — A pre-converted bf16, staging is pure uint4 copy)
// ---------------------------------------------------------------------------
template<int MODE>
__global__ __launch_bounds__(256) void proj_gemm(
    const unsigned short* __restrict__ Ahi, const unsigned short* __restrict__ Alo,
    const unsigned short* __restrict__ Bhi, const unsigned short* __restrict__ Blo,
    const float* __restrict__ bias,
    void* __restrict__ out0, unsigned short* __restrict__ out1)
{
    __shared__ __align__(16) short As[2][64][40];    // 32 k + 8 pad
    __shared__ __align__(16) short Bs[2][128][40];

    const int tid  = threadIdx.x;
    const int wave = tid >> 6, lane = tid & 63;
    const int quad = lane >> 4, lr = lane & 15;
    const int wy = wave >> 1, wx = wave & 1;
    const int m0 = blockIdx.x * 64, n0 = blockIdx.y * 128;

    f32x4 acc[2][4];
#pragma unroll
    for (int i = 0; i < 2; ++i)
#pragma unroll
        for (int j = 0; j < 4; ++j) acc[i][j] = (f32x4){0.f, 0.f, 0.f, 0.f};

    const int arow = tid >> 2, aseg = (tid & 3) * 8;   // A: 64 rows x 4 segs of 8
    const int brow = tid >> 1, bseg = (tid & 1) * 16;  // B: 128 rows x 2 segs of 16

    for (int k0 = 0; k0 < DM; k0 += 32) {
        __syncthreads();
        {
            const size_t ao = (size_t)(m0 + arow) * DM + k0 + aseg;
            *(uint4*)&As[0][arow][aseg] = *(const uint4*)&Ahi[ao];
            if (MODE == 0)
                *(uint4*)&As[1][arow][aseg] = *(const uint4*)&Alo[ao];
        }
        {
            const size_t bo = (size_t)(n0 + brow) * DM + k0 + bseg;
            *(uint4*)&Bs[0][brow][bseg]     = *(const uint4*)&Bhi[bo];
            *(uint4*)&Bs[0][brow][bseg + 8] = *(const uint4*)&Bhi[bo + 8];
            if (MODE == 0) {
                *(uint4*)&Bs[1][brow][bseg]     = *(const uint4*)&Blo[bo];
                *(uint4*)&Bs[1][brow][bseg + 8] = *(const uint4*)&Blo[bo + 8];
            }
        }
        __syncthreads();
        bf16x8 ah[2], al[2], bh[4], bl[4];
#pragma unroll
        for (int i = 0; i < 2; ++i) {
            ah[i] = *(const bf16x8*)&As[0][wy * 32 + i * 16 + lr][quad * 8];
            if (MODE == 0) al[i] = *(const bf16x8*)&As[1][wy * 32 + i * 16 + lr][quad * 8];
        }
#pragma unroll
        for (int j = 0; j < 4; ++j) {
            bh[j] = *(const bf16x8*)&Bs[0][wx * 64 + j * 16 + lr][quad * 8];
            if (MODE == 0) bl[j] = *(const bf16x8*)&Bs[1][wx * 64 + j * 16 + lr][quad * 8];
        }
#pragma unroll
        for (int i = 0; i < 2; ++i)
#pragma unroll
            for (int j = 0; j < 4; ++j) {
                acc[i][j] = __builtin_amdgcn_mfma_f32_16x16x32_bf16(ah[i], bh[j], acc[i][j], 0, 0, 0);
                if (MODE == 0) {
                    acc[i][j] = __builtin_amdgcn_mfma_f32_16x16x32_bf16(ah[i], bl[j], acc[i][j], 0, 0, 0);
                    acc[i][j] = __builtin_amdgcn_mfma_f32_16x16x32_bf16(al[i], bh[j], acc[i][j], 0, 0, 0);
                }
            }
    }

    float bj[4];
#pragma unroll
    for (int j = 0; j < 4; ++j) bj[j] = bias[n0 + wx * 64 + j * 16 + lr];

    if (MODE == 0) {
        unsigned short* Ohi = (unsigned short*)out0;
#pragma unroll
        for (int i = 0; i < 2; ++i) {
#pragma unroll
            for (int r = 0; r < 4; ++r) {
                float x[4];
#pragma unroll
                for (int j = 0; j < 4; ++j) x[j] = acc[i][j][r] + bj[j];
                float t = x[0] + x[1] + x[2] + x[3];
                t += __shfl_xor(t, 1, 16);
                t += __shfl_xor(t, 2, 16);
                t += __shfl_xor(t, 4, 16);
                t += __shfl_xor(t, 8, 16);
                const float mean = t * (1.0f / 64.0f);
                float ss = 0.f;
#pragma unroll
                for (int j = 0; j < 4; ++j) { x[j] -= mean; ss += x[j] * x[j]; }
                ss += __shfl_xor(ss, 1, 16);
                ss += __shfl_xor(ss, 2, 16);
                ss += __shfl_xor(ss, 4, 16);
                ss += __shfl_xor(ss, 8, 16);
                const float inv = 1.0f / fmaxf(sqrtf(ss), 1e-12f);
                const int row = m0 + wy * 32 + i * 16 + quad * 4 + r;
#pragma unroll
                for (int j = 0; j < 4; ++j) {
                    const float y = x[j] * inv;
                    const unsigned short hh = f2bf(y);
                    const unsigned short ll = f2bf(y - bf2f(hh));
                    const size_t o = (size_t)row * DM + n0 + wx * 64 + j * 16 + lr;
                    Ohi[o]  = hh;
                    out1[o] = ll;
                }
            }
        }
    } else if (MODE == 1) {
        unsigned short* Vg = (unsigned short*)out0;
        const int h = (n0 + wx * 64) >> 6;
#pragma unroll
        for (int i = 0; i < 2; ++i) {
            const int grow = m0 + wy * 32 + i * 16 + quad * 4;
            const int bb = grow >> 11, ss = grow & (SEQ - 1);
#pragma unroll
            for (int j = 0; j < 4; ++j) {
                const int d = j * 16 + lr;
                ushort4 pk;
                pk.x = f2bf(acc[i][j][0] + bj[j]);
                pk.y = f2bf(acc[i][j][1] + bj[j]);
                pk.z = f2bf(acc[i][j][2] + bj[j]);
                pk.w = f2bf(acc[i][j][3] + bj[j]);
                *(ushort4*)&Vg[((size_t)(bb * NH + h) * HD + d) * SEQ + ss] = pk;
            }
        }
    } else {
        float* O = (float*)out0;
#pragma unroll
        for (int i = 0; i < 2; ++i)
#pragma unroll
            for (int j = 0; j < 4; ++j)
#pragma unroll
                for (int r = 0; r < 4; ++r)
                    O[(size_t)(m0 + wy * 32 + i * 16 + quad * 4 + r) * DM +
                      n0 + wx * 64 + j * 16 + lr] = acc[i][j][r] + bj[j];
    }
}

// ---------------------------------------------------------------------------
// Fused attention, two-phase, MFMA. (R2 structure)
// Phase 1 computes ONLY row sums -> hi-only 2-term QK^T suffices: per-score
// bf16-level errors are independent & zero-mean across the 2048-column sum
// (denominator error ~0.05%), while phase-2 numerators keep full 6-term
// precision. Phase 1 stages only KHs (no KLs) -> half the staging.
// ---------------------------------------------------------------------------
__global__ __launch_bounds__(256) void attn_fused(
    const unsigned short* __restrict__ Qhi, const unsigned short* __restrict__ Qlo,
    const unsigned short* __restrict__ Khi, const unsigned short* __restrict__ Klo,
    const unsigned short* __restrict__ Vg,  const int* __restrict__ mask,
    const float* __restrict__ scale_p,
    float* __restrict__ attn, unsigned short* __restrict__ ctxb)
{
    __shared__ __align__(16) short KHs[64][72];
    __shared__ __align__(16) short KLs[64][72];
    __shared__ __align__(16) short Vs[64][72];
    __shared__ __align__(16) short Ps[64][72];
    __shared__ float mkf[64];

    const int tid = threadIdx.x;
    const int w = tid >> 6, lane = tid & 63;
    const int quad = lane >> 4, lr = lane & 15;

    // XCD-aware bijective swizzle: 1024 = 8 XCDs * 128 contiguous blocks
    const int lin = blockIdx.x;
    const int swz = (lin & 7) * 128 + (lin >> 3);
    const int b  = swz >> 9;
    const int h  = (swz >> 5) & 15;
    const int q0 = (swz & 31) * 64;

    const float scl = scale_p[0];
    const float s2 = scl * 1.44269504089f;
    const float c2 = -12.0f * 1.44269504089f;

    const int r0 = tid >> 3,        c0 = (tid & 7) * 8;
    const int r1 = (tid >> 3) + 32, c1 = (tid & 7) * 8;

    // ---- stage Q (KHs/KLs as temp), grab register fragments ----
    {
        const size_t base = ((size_t)(b * SEQ + q0)) * DM + h * HD;
        *(uint4*)&KHs[r0][c0] = *(const uint4*)&Qhi[base + (size_t)r0 * DM + c0];
        *(uint4*)&KHs[r1][c1] = *(const uint4*)&Qhi[base + (size_t)r1 * DM + c1];
        *(uint4*)&KLs[r0][c0] = *(const uint4*)&Qlo[base + (size_t)r0 * DM + c0];
        *(uint4*)&KLs[r1][c1] = *(const uint4*)&Qlo[base + (size_t)r1 * DM + c1];
    }
    __syncthreads();
    bf16x8 qh[2], ql[2];
#pragma unroll
    for (int kc = 0; kc < 2; ++kc) {
        qh[kc] = *(const bf16x8*)&KHs[w * 16 + lr][kc * 32 + quad * 8];
        ql[kc] = *(const bf16x8*)&KLs[w * 16 + lr][kc * 32 + quad * 8];
    }

    float rs[4] = {0.f, 0.f, 0.f, 0.f};

    // ---- phase 1: denominators (hi-only scores) ----
    for (int kt = 0; kt < SEQ / 64; ++kt) {
        const int kk = kt * 64;
        const size_t kb = ((size_t)(b * SEQ + kk)) * DM + h * HD;
        __syncthreads();
        *(uint4*)&KHs[r0][c0] = *(const uint4*)&Khi[kb + (size_t)r0 * DM + c0];
        *(uint4*)&KHs[r1][c1] = *(const uint4*)&Khi[kb + (size_t)r1 * DM + c1];
        if (tid < 64) mkf[tid] = mask[b * SEQ + kk + tid] ? c2 : -3.0e38f;
        __syncthreads();
#pragma unroll
        for (int j = 0; j < 4; ++j) {
            bf16x8 bh0 = *(const bf16x8*)&KHs[j * 16 + lr][quad * 8];
            bf16x8 bh1 = *(const bf16x8*)&KHs[j * 16 + lr][32 + quad * 8];
            f32x4 sa = (f32x4){0.f, 0.f, 0.f, 0.f};
            sa = __builtin_amdgcn_mfma_f32_16x16x32_bf16(qh[0], bh0, sa, 0, 0, 0);
            sa = __builtin_amdgcn_mfma_f32_16x16x32_bf16(qh[1], bh1, sa, 0, 0, 0);
            const float mo = mkf[j * 16 + lr];
#pragma unroll
            for (int r = 0; r < 4; ++r)
                rs[r] += exp2f(fmaf(sa[r], s2, mo));
        }
    }

    float rinv[4];
#pragma unroll
    for (int r = 0; r < 4; ++r) {
        float t = rs[r];
        t += __shfl_xor(t, 1, 16);
        t += __shfl_xor(t, 2, 16);
        t += __shfl_xor(t, 4, 16);
        t += __shfl_xor(t, 8, 16);
        rinv[r] = 1.0f / fmaxf(t, 1e-30f);
    }

    f32x4 acc_o[4];
#pragma unroll
    for (int dt = 0; dt < 4; ++dt) acc_o[dt] = (f32x4){0.f, 0.f, 0.f, 0.f};

    // ---- phase 2: attn store + PV (full 6-term precision) ----
    for (int kt = 0; kt < SEQ / 64; ++kt) {
        const int kk = kt * 64;
        const size_t kb = ((size_t)(b * SEQ + kk)) * DM + h * HD;
        const size_t vb = ((size_t)((b * NH + h) * HD)) * SEQ + kk;
        __syncthreads();
        *(uint4*)&KHs[r0][c0] = *(const uint4*)&Khi[kb + (size_t)r0 * DM + c0];
        *(uint4*)&KHs[r1][c1] = *(const uint4*)&Khi[kb + (size_t)r1 * DM + c1];
        *(uint4*)&KLs[r0][c0] = *(const uint4*)&Klo[kb + (size_t)r0 * DM + c0];
        *(uint4*)&KLs[r1][c1] = *(const uint4*)&Klo[kb + (size_t)r1 * DM + c1];
        *(uint4*)&Vs[r0][c0]  = *(const uint4*)&Vg[vb + (size_t)r0 * SEQ + c0];
        *(uint4*)&Vs[r1][c1]  = *(const uint4*)&Vg[vb + (size_t)r1 * SEQ + c1];
        if (tid < 64) mkf[tid] = mask[b * SEQ + kk + tid] ? c2 : -3.0e38f;
        __syncthreads();
#pragma unroll
        for (int j = 0; j < 4; ++j) {
            bf16x8 bh0 = *(const bf16x8*)&KHs[j * 16 + lr][quad * 8];
            bf16x8 bh1 = *(const bf16x8*)&KHs[j * 16 + lr][32 + quad * 8];
            bf16x8 bl0 = *(const bf16x8*)&KLs[j * 16 + lr][quad * 8];
            bf16x8 bl1 = *(const bf16x8*)&KLs[j * 16 + lr][32 + quad * 8];
            f32x4 sa = (f32x4){0.f, 0.f, 0.f, 0.f};
            sa = __builtin_amdgcn_mfma_f32_16x16x32_bf16(qh[0], bh0, sa, 0, 0, 0);
            sa = __builtin_amdgcn_mfma_f32_16x16x32_bf16(ql[0], bh0, sa, 0, 0, 0);
            sa = __builtin_amdgcn_mfma_f32_16x16x32_bf16(qh[0], bl0, sa, 0, 0, 0);
            sa = __builtin_amdgcn_mfma_f32_16x16x32_bf16(qh[1], bh1, sa, 0, 0, 0);
            sa = __builtin_amdgcn_mfma_f32_16x16x32_bf16(ql[1], bh1, sa, 0, 0, 0);
            sa = __builtin_amdgcn_mfma_f32_16x16x32_bf16(qh[1], bl1, sa, 0, 0, 0);
            const float mo = mkf[j * 16 + lr];
#pragma unroll
            for (int r = 0; r < 4; ++r) {
                const float pn = exp2f(fmaf(sa[r], s2, mo)) * rinv[r];
                const int qrow = q0 + w * 16 + quad * 4 + r;
                attn[((size_t)(b * NH + h) * SEQ + qrow) * SEQ + kk + j * 16 + lr] = pn;
                Ps[w * 16 + quad * 4 + r][j * 16 + lr] = (short)f2bf(pn);
            }
        }
        // PV: wave reads only its own Ps rows (written above) -> no barrier
        bf16x8 pa0 = *(const bf16x8*)&Ps[w * 16 + lr][quad * 8];
        bf16x8 pa1 = *(const bf16x8*)&Ps[w * 16 + lr][32 + quad * 8];
#pragma unroll
        for (int dt = 0; dt < 4; ++dt) {
            bf16x8 bv0 = *(const bf16x8*)&Vs[dt * 16 + lr][quad * 8];
            bf16x8 bv1 = *(const bf16x8*)&Vs[dt * 16 + lr][32 + quad * 8];
            acc_o[dt] = __builtin_amdgcn_mfma_f32_16x16x32_bf16(pa0, bv0, acc_o[dt], 0, 0, 0);
            acc_o[dt] = __builtin_amdgcn_mfma_f32_16x16x32_bf16(pa1, bv1, acc_o[dt], 0, 0, 0);
        }
    }

    // ---- ctx out (bf16, row-major [B,S,D]) ----
#pragma unroll
    for (int dt = 0; dt < 4; ++dt)
#pragma unroll
        for (int r = 0; r < 4; ++r)
            ctxb[((size_t)(b * SEQ + q0 + w * 16 + quad * 4 + r)) * DM +
                 h * HD + dt * 16 + lr] = (unsigned short)f2bf(acc_o[dt][r]);
}

// ---------------------------------------------------------------------------
extern "C" void kernel_launch(void* const* d_in, const int* in_sizes, int n_in,
                              void* d_out, int out_size, void* d_ws, size_t ws_size,
                              hipStream_t stream)
{
    const float* query = (const float*)d_in[0];
    const float* key   = (const float*)d_in[1];
    const float* value = (const float*)d_in[2];
    const int*   mask  = (const int*)d_in[3];
    const float* Wq = (const float*)d_in[4];
    const float* bq = (const float*)d_in[5];
    const float* Wk = (const float*)d_in[6];
    const float* bk = (const float*)d_in[7];
    const float* Wv = (const float*)d_in[8];
    const float* bv = (const float*)d_in[9];
    const float* Wo = (const float*)d_in[10];
    const float* bo = (const float*)d_in[11];
    const float* scale = (const float*)d_in[12];

    float* out_ctx  = (float*)d_out;                 // [B,S,DM]
    float* out_attn = out_ctx + (size_t)MR * DM;     // [B,NH,S,S]

    const size_t WSZ = (size_t)DM * DM;   // 1M elems
    const size_t TSZ = (size_t)MR * DM;   // 4M elems
    unsigned short* p = (unsigned short*)d_ws;
    unsigned short* Wq_hi = p; p += WSZ;
    unsigned short* Wq_lo = p; p += WSZ;
    unsigned short* Wk_hi = p; p += WSZ;
    unsigned short* Wk_lo = p; p += WSZ;
    unsigned short* Wv_b  = p; p += WSZ;
    unsigned short* Wo_b  = p; p += WSZ;
    unsigned short* Qn_hi = p; p += TSZ;
    unsigned short* Qn_lo = p; p += TSZ;
    unsigned short* Kn_hi = p; p += TSZ;
    unsigned short* Kn_lo = p; p += TSZ;
    unsigned short* Vg    = p; p += TSZ;
    // ctxb aliases Wq_hi..Wk_lo (4*WSZ == TSZ elems), dead after Q/K proj
    unsigned short* ctxb  = Wq_hi;
    // Activation pre-split scratch lives in the (not yet written) attn output
    unsigned short* Ahi = (unsigned short*)out_attn;
    unsigned short* Alo = Ahi + TSZ;

    convert_split <<<1024, 256, 0, stream>>>(Wq, Wq_hi, Wq_lo, 262144);
    convert_split <<<1024, 256, 0, stream>>>(Wk, Wk_hi, Wk_lo, 262144);
    convert_single<<<1024, 256, 0, stream>>>(Wv, Wv_b, 262144);
    convert_single<<<1024, 256, 0, stream>>>(Wo, Wo_b, 262144);

    dim3 gg(MR / 64, DM / 128);

    convert_split <<<4096, 256, 0, stream>>>(query, Ahi, Alo, (int)(TSZ / 4));
    proj_gemm<0><<<gg, 256, 0, stream>>>(Ahi, Alo, Wq_hi, Wq_lo, bq, Qn_hi, Qn_lo);
    convert_split <<<4096, 256, 0, stream>>>(key, Ahi, Alo, (int)(TSZ / 4));
    proj_gemm<0><<<gg, 256, 0, stream>>>(Ahi, Alo, Wk_hi, Wk_lo, bk, Kn_hi, Kn_lo);
    convert_single<<<4096, 256, 0, stream>>>(value, Ahi, (int)(TSZ / 4));
    proj_gemm<1><<<gg, 256, 0, stream>>>(Ahi, nullptr, Wv_b, nullptr, bv, Vg, nullptr);

    attn_fused<<<dim3(SEQ / 64 * NH * BATCH), 256, 0, stream>>>(
        Qn_hi, Qn_lo, Kn_hi, Kn_lo, Vg, mask, scale, out_attn, ctxb);

    proj_gemm<2><<<gg, 256, 0, stream>>>(ctxb, nullptr, Wo_b, nullptr, bo, out_ctx, nullptr);
}

// Round 15
// 862.237 us; speedup vs baseline: 1.2301x; 1.0433x over previous
//
#include <hip/hip_runtime.h>
#include <math.h>

#define DM   1024
#define NH   16
#define HD   64
#define BATCH 2
#define SEQ  2048
#define MR   (BATCH*SEQ)   // 4096 rows

typedef __attribute__((ext_vector_type(8))) short bf16x8;
typedef __attribute__((ext_vector_type(4))) float f32x4;

__device__ __forceinline__ unsigned short f2bf(float x) {
    unsigned u = __builtin_bit_cast(unsigned, x);
    u = (u + 0x7FFFu + ((u >> 16) & 1u)) >> 16;
    return (unsigned short)u;
}
__device__ __forceinline__ float bf2f(unsigned short s) {
    unsigned u = ((unsigned)s) << 16;
    return __builtin_bit_cast(float, u);
}

// ---------------------------------------------------------------------------
// fp32 -> bf16 split (hi + lo) / single conversions
// ---------------------------------------------------------------------------
__global__ __launch_bounds__(256) void convert_split(
    const float* __restrict__ src, unsigned short* __restrict__ hi,
    unsigned short* __restrict__ lo, int n4)
{
    int i = blockIdx.x * 256 + threadIdx.x;
    if (i >= n4) return;
    float4 v = ((const float4*)src)[i];
    float f[4] = {v.x, v.y, v.z, v.w};
    unsigned short h[4], l[4];
#pragma unroll
    for (int k = 0; k < 4; ++k) {
        h[k] = f2bf(f[k]);
        l[k] = f2bf(f[k] - bf2f(h[k]));
    }
    ((ushort4*)hi)[i] = make_ushort4(h[0], h[1], h[2], h[3]);
    ((ushort4*)lo)[i] = make_ushort4(l[0], l[1], l[2], l[3]);
}

__global__ __launch_bounds__(256) void convert_single(
    const float* __restrict__ src, unsigned short* __restrict__ dst, int n4)
{
    int i = blockIdx.x * 256 + threadIdx.x;
    if (i >= n4) return;
    float4 v = ((const float4*)src)[i];
    ((ushort4*)dst)[i] = make_ushort4(f2bf(v.x), f2bf(v.y), f2bf(v.z), f2bf(v.w));
}

// ---------------------------------------------------------------------------
// MFMA projection GEMM: C[M,1024] = A[M,1024] @ W[1024,1024]^T + bias
// (unchanged from R7)
// ---------------------------------------------------------------------------
template<int MODE>
__global__ __launch_bounds__(256) void proj_gemm(
    const unsigned short* __restrict__ Ahi, const unsigned short* __restrict__ Alo,
    const unsigned short* __restrict__ Bhi, const unsigned short* __restrict__ Blo,
    const float* __restrict__ bias,
    void* __restrict__ out0, unsigned short* __restrict__ out1)
{
    __shared__ __align__(16) short As[2][64][40];    // 32 k + 8 pad
    __shared__ __align__(16) short Bs[2][128][40];

    const int tid  = threadIdx.x;
    const int wave = tid >> 6, lane = tid & 63;
    const int quad = lane >> 4, lr = lane & 15;
    const int wy = wave >> 1, wx = wave & 1;
    const int m0 = blockIdx.x * 64, n0 = blockIdx.y * 128;

    f32x4 acc[2][4];
#pragma unroll
    for (int i = 0; i < 2; ++i)
#pragma unroll
        for (int j = 0; j < 4; ++j) acc[i][j] = (f32x4){0.f, 0.f, 0.f, 0.f};

    const int arow = tid >> 2, aseg = (tid & 3) * 8;   // A: 64 rows x 4 segs of 8
    const int brow = tid >> 1, bseg = (tid & 1) * 16;  // B: 128 rows x 2 segs of 16

    for (int k0 = 0; k0 < DM; k0 += 32) {
        __syncthreads();
        {
            const size_t ao = (size_t)(m0 + arow) * DM + k0 + aseg;
            *(uint4*)&As[0][arow][aseg] = *(const uint4*)&Ahi[ao];
            if (MODE == 0)
                *(uint4*)&As[1][arow][aseg] = *(const uint4*)&Alo[ao];
        }
        {
            const size_t bo = (size_t)(n0 + brow) * DM + k0 + bseg;
            *(uint4*)&Bs[0][brow][bseg]     = *(const uint4*)&Bhi[bo];
            *(uint4*)&Bs[0][brow][bseg + 8] = *(const uint4*)&Bhi[bo + 8];
            if (MODE == 0) {
                *(uint4*)&Bs[1][brow][bseg]     = *(const uint4*)&Blo[bo];
                *(uint4*)&Bs[1][brow][bseg + 8] = *(const uint4*)&Blo[bo + 8];
            }
        }
        __syncthreads();
        bf16x8 ah[2], al[2], bh[4], bl[4];
#pragma unroll
        for (int i = 0; i < 2; ++i) {
            ah[i] = *(const bf16x8*)&As[0][wy * 32 + i * 16 + lr][quad * 8];
            if (MODE == 0) al[i] = *(const bf16x8*)&As[1][wy * 32 + i * 16 + lr][quad * 8];
        }
#pragma unroll
        for (int j = 0; j < 4; ++j) {
            bh[j] = *(const bf16x8*)&Bs[0][wx * 64 + j * 16 + lr][quad * 8];
            if (MODE == 0) bl[j] = *(const bf16x8*)&Bs[1][wx * 64 + j * 16 + lr][quad * 8];
        }
#pragma unroll
        for (int i = 0; i < 2; ++i)
#pragma unroll
            for (int j = 0; j < 4; ++j) {
                acc[i][j] = __builtin_amdgcn_mfma_f32_16x16x32_bf16(ah[i], bh[j], acc[i][j], 0, 0, 0);
                if (MODE == 0) {
                    acc[i][j] = __builtin_amdgcn_mfma_f32_16x16x32_bf16(ah[i], bl[j], acc[i][j], 0, 0, 0);
                    acc[i][j] = __builtin_amdgcn_mfma_f32_16x16x32_bf16(al[i], bh[j], acc[i][j], 0, 0, 0);
                }
            }
    }

    float bj[4];
#pragma unroll
    for (int j = 0; j < 4; ++j) bj[j] = bias[n0 + wx * 64 + j * 16 + lr];

    if (MODE == 0) {
        unsigned short* Ohi = (unsigned short*)out0;
#pragma unroll
        for (int i = 0; i < 2; ++i) {
#pragma unroll
            for (int r = 0; r < 4; ++r) {
                float x[4];
#pragma unroll
                for (int j = 0; j < 4; ++j) x[j] = acc[i][j][r] + bj[j];
                float t = x[0] + x[1] + x[2] + x[3];
                t += __shfl_xor(t, 1, 16);
                t += __shfl_xor(t, 2, 16);
                t += __shfl_xor(t, 4, 16);
                t += __shfl_xor(t, 8, 16);
                const float mean = t * (1.0f / 64.0f);
                float ss = 0.f;
#pragma unroll
                for (int j = 0; j < 4; ++j) { x[j] -= mean; ss += x[j] * x[j]; }
                ss += __shfl_xor(ss, 1, 16);
                ss += __shfl_xor(ss, 2, 16);
                ss += __shfl_xor(ss, 4, 16);
                ss += __shfl_xor(ss, 8, 16);
                const float inv = 1.0f / fmaxf(sqrtf(ss), 1e-12f);
                const int row = m0 + wy * 32 + i * 16 + quad * 4 + r;
#pragma unroll
                for (int j = 0; j < 4; ++j) {
                    const float y = x[j] * inv;
                    const unsigned short hh = f2bf(y);
                    const unsigned short ll = f2bf(y - bf2f(hh));
                    const size_t o = (size_t)row * DM + n0 + wx * 64 + j * 16 + lr;
                    Ohi[o]  = hh;
                    out1[o] = ll;
                }
            }
        }
    } else if (MODE == 1) {
        unsigned short* Vg = (unsigned short*)out0;
        const int h = (n0 + wx * 64) >> 6;
#pragma unroll
        for (int i = 0; i < 2; ++i) {
            const int grow = m0 + wy * 32 + i * 16 + quad * 4;
            const int bb = grow >> 11, ss = grow & (SEQ - 1);
#pragma unroll
            for (int j = 0; j < 4; ++j) {
                const int d = j * 16 + lr;
                ushort4 pk;
                pk.x = f2bf(acc[i][j][0] + bj[j]);
                pk.y = f2bf(acc[i][j][1] + bj[j]);
                pk.z = f2bf(acc[i][j][2] + bj[j]);
                pk.w = f2bf(acc[i][j][3] + bj[j]);
                *(ushort4*)&Vg[((size_t)(bb * NH + h) * HD + d) * SEQ + ss] = pk;
            }
        }
    } else {
        float* O = (float*)out0;
#pragma unroll
        for (int i = 0; i < 2; ++i)
#pragma unroll
            for (int j = 0; j < 4; ++j)
#pragma unroll
                for (int r = 0; r < 4; ++r)
                    O[(size_t)(m0 + wy * 32 + i * 16 + quad * 4 + r) * DM +
                      n0 + wx * 64 + j * 16 + lr] = acc[i][j][r] + bj[j];
    }
}

// ---------------------------------------------------------------------------
// Fused attention, two-phase, MFMA. QBLK=128, 512 threads (8 waves), each
// wave owns one 16-row q-strip. Per-wave arithmetic identical to R7; each
// staged K/V panel now serves 128 q-rows -> staging traffic, barriers and
// K/V re-reads per q-row are HALVED. Q fragments load direct from global.
// Phase 1 hi-only (verified R7). Grid 512 = 8 XCDs x 64, bijective swizzle.
// ---------------------------------------------------------------------------
__global__ __launch_bounds__(512) void attn_fused(
    const unsigned short* __restrict__ Qhi, const unsigned short* __restrict__ Qlo,
    const unsigned short* __restrict__ Khi, const unsigned short* __restrict__ Klo,
    const unsigned short* __restrict__ Vg,  const int* __restrict__ mask,
    const float* __restrict__ scale_p,
    float* __restrict__ attn, unsigned short* __restrict__ ctxb)
{
    __shared__ __align__(16) short KHs[64][72];
    __shared__ __align__(16) short KLs[64][72];
    __shared__ __align__(16) short Vs[64][72];
    __shared__ __align__(16) short Ps[128][72];
    __shared__ float mkf[64];

    const int tid = threadIdx.x;           // 0..511
    const int w = tid >> 6, lane = tid & 63;
    const int quad = lane >> 4, lr = lane & 15;

    // XCD-aware bijective swizzle: 512 = 8 XCDs * 64 contiguous blocks
    const int lin = blockIdx.x;
    const int swz = (lin & 7) * 64 + (lin >> 3);
    const int b  = swz >> 8;               // 256 blocks per batch
    const int h  = (swz >> 4) & 15;        // 16 q-tiles per (b,h)
    const int q0 = (swz & 15) * 128;

    const float scl = scale_p[0];
    const float s2 = scl * 1.44269504089f;
    const float c2 = -12.0f * 1.44269504089f;

    // staging: 512 threads cover one 64x64 bf16 tile with 1 uint4 each
    const int r0 = tid >> 3, c0 = (tid & 7) * 8;

    // ---- Q fragments direct from global (one-time) ----
    bf16x8 qh[2], ql[2];
    {
        const size_t qbase = ((size_t)(b * SEQ + q0 + w * 16 + lr)) * DM + h * HD;
#pragma unroll
        for (int kc = 0; kc < 2; ++kc) {
            qh[kc] = *(const bf16x8*)&Qhi[qbase + kc * 32 + quad * 8];
            ql[kc] = *(const bf16x8*)&Qlo[qbase + kc * 32 + quad * 8];
        }
    }

    float rs[4] = {0.f, 0.f, 0.f, 0.f};

    // ---- phase 1: denominators (hi-only scores) ----
    for (int kt = 0; kt < SEQ / 64; ++kt) {
        const int kk = kt * 64;
        const size_t kb = ((size_t)(b * SEQ + kk)) * DM + h * HD;
        __syncthreads();
        *(uint4*)&KHs[r0][c0] = *(const uint4*)&Khi[kb + (size_t)r0 * DM + c0];
        if (tid < 64) mkf[tid] = mask[b * SEQ + kk + tid] ? c2 : -3.0e38f;
        __syncthreads();
#pragma unroll
        for (int j = 0; j < 4; ++j) {
            bf16x8 bh0 = *(const bf16x8*)&KHs[j * 16 + lr][quad * 8];
            bf16x8 bh1 = *(const bf16x8*)&KHs[j * 16 + lr][32 + quad * 8];
            f32x4 sa = (f32x4){0.f, 0.f, 0.f, 0.f};
            sa = __builtin_amdgcn_mfma_f32_16x16x32_bf16(qh[0], bh0, sa, 0, 0, 0);
            sa = __builtin_amdgcn_mfma_f32_16x16x32_bf16(qh[1], bh1, sa, 0, 0, 0);
            const float mo = mkf[j * 16 + lr];
#pragma unroll
            for (int r = 0; r < 4; ++r)
                rs[r] += exp2f(fmaf(sa[r], s2, mo));
        }
    }

    float rinv[4];
#pragma unroll
    for (int r = 0; r < 4; ++r) {
        float t = rs[r];
        t += __shfl_xor(t, 1, 16);
        t += __shfl_xor(t, 2, 16);
        t += __shfl_xor(t, 4, 16);
        t += __shfl_xor(t, 8, 16);
        rinv[r] = 1.0f / fmaxf(t, 1e-30f);
    }

    f32x4 acc_o[4];
#pragma unroll
    for (int dt = 0; dt < 4; ++dt) acc_o[dt] = (f32x4){0.f, 0.f, 0.f, 0.f};

    // ---- phase 2: attn store + PV (full 6-term precision) ----
    for (int kt = 0; kt < SEQ / 64; ++kt) {
        const int kk = kt * 64;
        const size_t kb = ((size_t)(b * SEQ + kk)) * DM + h * HD;
        const size_t vb = ((size_t)((b * NH + h) * HD)) * SEQ + kk;
        __syncthreads();
        *(uint4*)&KHs[r0][c0] = *(const uint4*)&Khi[kb + (size_t)r0 * DM + c0];
        *(uint4*)&KLs[r0][c0] = *(const uint4*)&Klo[kb + (size_t)r0 * DM + c0];
        *(uint4*)&Vs[r0][c0]  = *(const uint4*)&Vg[vb + (size_t)r0 * SEQ + c0];
        if (tid < 64) mkf[tid] = mask[b * SEQ + kk + tid] ? c2 : -3.0e38f;
        __syncthreads();
#pragma unroll
        for (int j = 0; j < 4; ++j) {
            bf16x8 bh0 = *(const bf16x8*)&KHs[j * 16 + lr][quad * 8];
            bf16x8 bh1 = *(const bf16x8*)&KHs[j * 16 + lr][32 + quad * 8];
            bf16x8 bl0 = *(const bf16x8*)&KLs[j * 16 + lr][quad * 8];
            bf16x8 bl1 = *(const bf16x8*)&KLs[j * 16 + lr][32 + quad * 8];
            f32x4 sa = (f32x4){0.f, 0.f, 0.f, 0.f};
            sa = __builtin_amdgcn_mfma_f32_16x16x32_bf16(qh[0], bh0, sa, 0, 0, 0);
            sa = __builtin_amdgcn_mfma_f32_16x16x32_bf16(ql[0], bh0, sa, 0, 0, 0);
            sa = __builtin_amdgcn_mfma_f32_16x16x32_bf16(qh[0], bl0, sa, 0, 0, 0);
            sa = __builtin_amdgcn_mfma_f32_16x16x32_bf16(qh[1], bh1, sa, 0, 0, 0);
            sa = __builtin_amdgcn_mfma_f32_16x16x32_bf16(ql[1], bh1, sa, 0, 0, 0);
            sa = __builtin_amdgcn_mfma_f32_16x16x32_bf16(qh[1], bl1, sa, 0, 0, 0);
            const float mo = mkf[j * 16 + lr];
#pragma unroll
            for (int r = 0; r < 4; ++r) {
                const float pn = exp2f(fmaf(sa[r], s2, mo)) * rinv[r];
                const int qrow = q0 + w * 16 + quad * 4 + r;
                attn[((size_t)(b * NH + h) * SEQ + qrow) * SEQ + kk + j * 16 + lr] = pn;
                Ps[w * 16 + quad * 4 + r][j * 16 + lr] = (short)f2bf(pn);
            }
        }
        // PV: wave reads only its own Ps rows (written above) -> no barrier
        bf16x8 pa0 = *(const bf16x8*)&Ps[w * 16 + lr][quad * 8];
        bf16x8 pa1 = *(const bf16x8*)&Ps[w * 16 + lr][32 + quad * 8];
#pragma unroll
        for (int dt = 0; dt < 4; ++dt) {
            bf16x8 bv0 = *(const bf16x8*)&Vs[dt * 16 + lr][quad * 8];
            bf16x8 bv1 = *(const bf16x8*)&Vs[dt * 16 + lr][32 + quad * 8];
            acc_o[dt] = __builtin_amdgcn_mfma_f32_16x16x32_bf16(pa0, bv0, acc_o[dt], 0, 0, 0);
            acc_o[dt] = __builtin_amdgcn_mfma_f32_16x16x32_bf16(pa1, bv1, acc_o[dt], 0, 0, 0);
        }
    }

    // ---- ctx out (bf16, row-major [B,S,D]) ----
#pragma unroll
    for (int dt = 0; dt < 4; ++dt)
#pragma unroll
        for (int r = 0; r < 4; ++r)
            ctxb[((size_t)(b * SEQ + q0 + w * 16 + quad * 4 + r)) * DM +
                 h * HD + dt * 16 + lr] = (unsigned short)f2bf(acc_o[dt][r]);
}

// ---------------------------------------------------------------------------
extern "C" void kernel_launch(void* const* d_in, const int* in_sizes, int n_in,
                              void* d_out, int out_size, void* d_ws, size_t ws_size,
                              hipStream_t stream)
{
    const float* query = (const float*)d_in[0];
    const float* key   = (const float*)d_in[1];
    const float* value = (const float*)d_in[2];
    const int*   mask  = (const int*)d_in[3];
    const float* Wq = (const float*)d_in[4];
    const float* bq = (const float*)d_in[5];
    const float* Wk = (const float*)d_in[6];
    const float* bk = (const float*)d_in[7];
    const float* Wv = (const float*)d_in[8];
    const float* bv = (const float*)d_in[9];
    const float* Wo = (const float*)d_in[10];
    const float* bo = (const float*)d_in[11];
    const float* scale = (const float*)d_in[12];

    float* out_ctx  = (float*)d_out;                 // [B,S,DM]
    float* out_attn = out_ctx + (size_t)MR * DM;     // [B,NH,S,S]

    const size_t WSZ = (size_t)DM * DM;   // 1M elems
    const size_t TSZ = (size_t)MR * DM;   // 4M elems
    unsigned short* p = (unsigned short*)d_ws;
    unsigned short* Wq_hi = p; p += WSZ;
    unsigned short* Wq_lo = p; p += WSZ;
    unsigned short* Wk_hi = p; p += WSZ;
    unsigned short* Wk_lo = p; p += WSZ;
    unsigned short* Wv_b  = p; p += WSZ;
    unsigned short* Wo_b  = p; p += WSZ;
    unsigned short* Qn_hi = p; p += TSZ;
    unsigned short* Qn_lo = p; p += TSZ;
    unsigned short* Kn_hi = p; p += TSZ;
    unsigned short* Kn_lo = p; p += TSZ;
    unsigned short* Vg    = p; p += TSZ;
    // ctxb aliases Wq_hi..Wk_lo (4*WSZ == TSZ elems), dead after Q/K proj
    unsigned short* ctxb  = Wq_hi;
    // Activation pre-split scratch lives in the (not yet written) attn output
    unsigned short* Ahi = (unsigned short*)out_attn;
    unsigned short* Alo = Ahi + TSZ;

    convert_split <<<1024, 256, 0, stream>>>(Wq, Wq_hi, Wq_lo, 262144);
    convert_split <<<1024, 256, 0, stream>>>(Wk, Wk_hi, Wk_lo, 262144);
    convert_single<<<1024, 256, 0, stream>>>(Wv, Wv_b, 262144);
    convert_single<<<1024, 256, 0, stream>>>(Wo, Wo_b, 262144);

    dim3 gg(MR / 64, DM / 128);

    convert_split <<<4096, 256, 0, stream>>>(query, Ahi, Alo, (int)(TSZ / 4));
    proj_gemm<0><<<gg, 256, 0, stream>>>(Ahi, Alo, Wq_hi, Wq_lo, bq, Qn_hi, Qn_lo);
    convert_split <<<4096, 256, 0, stream>>>(key, Ahi, Alo, (int)(TSZ / 4));
    proj_gemm<0><<<gg, 256, 0, stream>>>(Ahi, Alo, Wk_hi, Wk_lo, bk, Kn_hi, Kn_lo);
    convert_single<<<4096, 256, 0, stream>>>(value, Ahi, (int)(TSZ / 4));
    proj_gemm<1><<<gg, 256, 0, stream>>>(Ahi, nullptr, Wv_b, nullptr, bv, Vg, nullptr);

    attn_fused<<<dim3(SEQ / 128 * NH * BATCH), 512, 0, stream>>>(
        Qn_hi, Qn_lo, Kn_hi, Kn_lo, Vg, mask, scale, out_attn, ctxb);

    proj_gemm<2><<<gg, 256, 0, stream>>>(ctxb, nullptr, Wo_b, nullptr, bo, out_ctx, nullptr);
}

// Round 20
// 823.941 us; speedup vs baseline: 1.2873x; 1.0465x over previous
//
#include <hip/hip_runtime.h>
#include <math.h>

#define DM   1024
#define NH   16
#define HD   64
#define BATCH 2
#define SEQ  2048
#define MR   (BATCH*SEQ)   // 4096 rows

typedef __attribute__((ext_vector_type(8))) short bf16x8;
typedef __attribute__((ext_vector_type(4))) float f32x4;

__device__ __forceinline__ unsigned short f2bf(float x) {
    unsigned u = __builtin_bit_cast(unsigned, x);
    u = (u + 0x7FFFu + ((u >> 16) & 1u)) >> 16;
    return (unsigned short)u;
}
__device__ __forceinline__ float bf2f(unsigned short s) {
    unsigned u = ((unsigned)s) << 16;
    return __builtin_bit_cast(float, u);
}

// ---------------------------------------------------------------------------
// fp32 -> bf16 split (hi + lo) / single conversions
// ---------------------------------------------------------------------------
__global__ __launch_bounds__(256) void convert_split(
    const float* __restrict__ src, unsigned short* __restrict__ hi,
    unsigned short* __restrict__ lo, int n4)
{
    int i = blockIdx.x * 256 + threadIdx.x;
    if (i >= n4) return;
    float4 v = ((const float4*)src)[i];
    float f[4] = {v.x, v.y, v.z, v.w};
    unsigned short h[4], l[4];
#pragma unroll
    for (int k = 0; k < 4; ++k) {
        h[k] = f2bf(f[k]);
        l[k] = f2bf(f[k] - bf2f(h[k]));
    }
    ((ushort4*)hi)[i] = make_ushort4(h[0], h[1], h[2], h[3]);
    ((ushort4*)lo)[i] = make_ushort4(l[0], l[1], l[2], l[3]);
}

__global__ __launch_bounds__(256) void convert_single(
    const float* __restrict__ src, unsigned short* __restrict__ dst, int n4)
{
    int i = blockIdx.x * 256 + threadIdx.x;
    if (i >= n4) return;
    float4 v = ((const float4*)src)[i];
    ((ushort4*)dst)[i] = make_ushort4(f2bf(v.x), f2bf(v.y), f2bf(v.z), f2bf(v.w));
}

// ---------------------------------------------------------------------------
// MFMA projection GEMM: C[M,1024] = A[M,1024] @ W[1024,1024]^T + bias
// (unchanged from R15)
// ---------------------------------------------------------------------------
template<int MODE>
__global__ __launch_bounds__(256) void proj_gemm(
    const unsigned short* __restrict__ Ahi, const unsigned short* __restrict__ Alo,
    const unsigned short* __restrict__ Bhi, const unsigned short* __restrict__ Blo,
    const float* __restrict__ bias,
    void* __restrict__ out0, unsigned short* __restrict__ out1)
{
    __shared__ __align__(16) short As[2][64][40];    // 32 k + 8 pad
    __shared__ __align__(16) short Bs[2][128][40];

    const int tid  = threadIdx.x;
    const int wave = tid >> 6, lane = tid & 63;
    const int quad = lane >> 4, lr = lane & 15;
    const int wy = wave >> 1, wx = wave & 1;
    const int m0 = blockIdx.x * 64, n0 = blockIdx.y * 128;

    f32x4 acc[2][4];
#pragma unroll
    for (int i = 0; i < 2; ++i)
#pragma unroll
        for (int j = 0; j < 4; ++j) acc[i][j] = (f32x4){0.f, 0.f, 0.f, 0.f};

    const int arow = tid >> 2, aseg = (tid & 3) * 8;   // A: 64 rows x 4 segs of 8
    const int brow = tid >> 1, bseg = (tid & 1) * 16;  // B: 128 rows x 2 segs of 16

    for (int k0 = 0; k0 < DM; k0 += 32) {
        __syncthreads();
        {
            const size_t ao = (size_t)(m0 + arow) * DM + k0 + aseg;
            *(uint4*)&As[0][arow][aseg] = *(const uint4*)&Ahi[ao];
            if (MODE == 0)
                *(uint4*)&As[1][arow][aseg] = *(const uint4*)&Alo[ao];
        }
        {
            const size_t bo = (size_t)(n0 + brow) * DM + k0 + bseg;
            *(uint4*)&Bs[0][brow][bseg]     = *(const uint4*)&Bhi[bo];
            *(uint4*)&Bs[0][brow][bseg + 8] = *(const uint4*)&Bhi[bo + 8];
            if (MODE == 0) {
                *(uint4*)&Bs[1][brow][bseg]     = *(const uint4*)&Blo[bo];
                *(uint4*)&Bs[1][brow][bseg + 8] = *(const uint4*)&Blo[bo + 8];
            }
        }
        __syncthreads();
        bf16x8 ah[2], al[2], bh[4], bl[4];
#pragma unroll
        for (int i = 0; i < 2; ++i) {
            ah[i] = *(const bf16x8*)&As[0][wy * 32 + i * 16 + lr][quad * 8];
            if (MODE == 0) al[i] = *(const bf16x8*)&As[1][wy * 32 + i * 16 + lr][quad * 8];
        }
#pragma unroll
        for (int j = 0; j < 4; ++j) {
            bh[j] = *(const bf16x8*)&Bs[0][wx * 64 + j * 16 + lr][quad * 8];
            if (MODE == 0) bl[j] = *(const bf16x8*)&Bs[1][wx * 64 + j * 16 + lr][quad * 8];
        }
#pragma unroll
        for (int i = 0; i < 2; ++i)
#pragma unroll
            for (int j = 0; j < 4; ++j) {
                acc[i][j] = __builtin_amdgcn_mfma_f32_16x16x32_bf16(ah[i], bh[j], acc[i][j], 0, 0, 0);
                if (MODE == 0) {
                    acc[i][j] = __builtin_amdgcn_mfma_f32_16x16x32_bf16(ah[i], bl[j], acc[i][j], 0, 0, 0);
                    acc[i][j] = __builtin_amdgcn_mfma_f32_16x16x32_bf16(al[i], bh[j], acc[i][j], 0, 0, 0);
                }
            }
    }

    float bj[4];
#pragma unroll
    for (int j = 0; j < 4; ++j) bj[j] = bias[n0 + wx * 64 + j * 16 + lr];

    if (MODE == 0) {
        unsigned short* Ohi = (unsigned short*)out0;
#pragma unroll
        for (int i = 0; i < 2; ++i) {
#pragma unroll
            for (int r = 0; r < 4; ++r) {
                float x[4];
#pragma unroll
                for (int j = 0; j < 4; ++j) x[j] = acc[i][j][r] + bj[j];
                float t = x[0] + x[1] + x[2] + x[3];
                t += __shfl_xor(t, 1, 16);
                t += __shfl_xor(t, 2, 16);
                t += __shfl_xor(t, 4, 16);
                t += __shfl_xor(t, 8, 16);
                const float mean = t * (1.0f / 64.0f);
                float ss = 0.f;
#pragma unroll
                for (int j = 0; j < 4; ++j) { x[j] -= mean; ss += x[j] * x[j]; }
                ss += __shfl_xor(ss, 1, 16);
                ss += __shfl_xor(ss, 2, 16);
                ss += __shfl_xor(ss, 4, 16);
                ss += __shfl_xor(ss, 8, 16);
                const float inv = 1.0f / fmaxf(sqrtf(ss), 1e-12f);
                const int row = m0 + wy * 32 + i * 16 + quad * 4 + r;
#pragma unroll
                for (int j = 0; j < 4; ++j) {
                    const float y = x[j] * inv;
                    const unsigned short hh = f2bf(y);
                    const unsigned short ll = f2bf(y - bf2f(hh));
                    const size_t o = (size_t)row * DM + n0 + wx * 64 + j * 16 + lr;
                    Ohi[o]  = hh;
                    out1[o] = ll;
                }
            }
        }
    } else if (MODE == 1) {
        unsigned short* Vg = (unsigned short*)out0;
        const int h = (n0 + wx * 64) >> 6;
#pragma unroll
        for (int i = 0; i < 2; ++i) {
            const int grow = m0 + wy * 32 + i * 16 + quad * 4;
            const int bb = grow >> 11, ss = grow & (SEQ - 1);
#pragma unroll
            for (int j = 0; j < 4; ++j) {
                const int d = j * 16 + lr;
                ushort4 pk;
                pk.x = f2bf(acc[i][j][0] + bj[j]);
                pk.y = f2bf(acc[i][j][1] + bj[j]);
                pk.z = f2bf(acc[i][j][2] + bj[j]);
                pk.w = f2bf(acc[i][j][3] + bj[j]);
                *(ushort4*)&Vg[((size_t)(bb * NH + h) * HD + d) * SEQ + ss] = pk;
            }
        }
    } else {
        float* O = (float*)out0;
#pragma unroll
        for (int i = 0; i < 2; ++i)
#pragma unroll
            for (int j = 0; j < 4; ++j)
#pragma unroll
                for (int r = 0; r < 4; ++r)
                    O[(size_t)(m0 + wy * 32 + i * 16 + quad * 4 + r) * DM +
                      n0 + wx * 64 + j * 16 + lr] = acc[i][j][r] + bj[j];
    }
}

// ---------------------------------------------------------------------------
// Fused attention, two-phase, MFMA. QBLK=128, 512 threads (8 waves).
// R16 change (T14 async-STAGE split): next tile's K/V/mask prefetched into
// REGISTERS during current tile's compute; regs->LDS at top of next iter.
// Barriers are raw s_barrier with lgkmcnt(0)-only waits so the in-flight
// vmcnt prefetch loads are NOT drained at the barrier (plain __syncthreads
// would drain vmcnt and defeat the prefetch). Correct: LDS writes ordered by
// lgkmcnt; vmcnt loads target per-wave regs (no cross-wave hazard).
// Arithmetic bit-identical to R15.
// ---------------------------------------------------------------------------
__global__ __launch_bounds__(512) void attn_fused(
    const unsigned short* __restrict__ Qhi, const unsigned short* __restrict__ Qlo,
    const unsigned short* __restrict__ Khi, const unsigned short* __restrict__ Klo,
    const unsigned short* __restrict__ Vg,  const int* __restrict__ mask,
    const float* __restrict__ scale_p,
    float* __restrict__ attn, unsigned short* __restrict__ ctxb)
{
    __shared__ __align__(16) short KHs[64][72];
    __shared__ __align__(16) short KLs[64][72];
    __shared__ __align__(16) short Vs[64][72];
    __shared__ __align__(16) short Ps[128][72];
    __shared__ float mkf[64];

    const int tid = threadIdx.x;           // 0..511
    const int w = tid >> 6, lane = tid & 63;
    const int quad = lane >> 4, lr = lane & 15;

    // XCD-aware bijective swizzle: 512 = 8 XCDs * 64 contiguous blocks
    const int lin = blockIdx.x;
    const int swz = (lin & 7) * 64 + (lin >> 3);
    const int b  = swz >> 8;               // 256 blocks per batch
    const int h  = (swz >> 4) & 15;        // 16 q-tiles per (b,h)
    const int q0 = (swz & 15) * 128;

    const float scl = scale_p[0];
    const float s2 = scl * 1.44269504089f;
    const float c2 = -12.0f * 1.44269504089f;

    // staging: 512 threads cover one 64x64 bf16 tile with 1 uint4 each
    const int r0 = tid >> 3, c0 = (tid & 7) * 8;

    // ---- Q fragments direct from global (one-time) ----
    bf16x8 qh[2], ql[2];
    {
        const size_t qbase = ((size_t)(b * SEQ + q0 + w * 16 + lr)) * DM + h * HD;
#pragma unroll
        for (int kc = 0; kc < 2; ++kc) {
            qh[kc] = *(const bf16x8*)&Qhi[qbase + kc * 32 + quad * 8];
            ql[kc] = *(const bf16x8*)&Qlo[qbase + kc * 32 + quad * 8];
        }
    }

    float rs[4] = {0.f, 0.f, 0.f, 0.f};

    // ---- phase 1: denominators (hi-only scores), T14 prefetch ----
    uint4 pKH; int pmk = 0;
    {
        const size_t kb = ((size_t)(b * SEQ)) * DM + h * HD;
        pKH = *(const uint4*)&Khi[kb + (size_t)r0 * DM + c0];
        if (tid < 64) pmk = mask[b * SEQ + tid];
    }
    for (int kt = 0; kt < SEQ / 64; ++kt) {
        asm volatile("s_waitcnt lgkmcnt(0)" ::: "memory");
        __builtin_amdgcn_s_barrier();
        __builtin_amdgcn_sched_barrier(0);
        *(uint4*)&KHs[r0][c0] = pKH;               // vmcnt wait auto-inserted
        if (tid < 64) mkf[tid] = pmk ? c2 : -3.0e38f;
        if (kt + 1 < SEQ / 64) {                   // issue next tile's loads
            const int kk1 = (kt + 1) * 64;
            const size_t kb = ((size_t)(b * SEQ + kk1)) * DM + h * HD;
            pKH = *(const uint4*)&Khi[kb + (size_t)r0 * DM + c0];
            if (tid < 64) pmk = mask[b * SEQ + kk1 + tid];
        }
        asm volatile("s_waitcnt lgkmcnt(0)" ::: "memory");
        __builtin_amdgcn_s_barrier();
        __builtin_amdgcn_sched_barrier(0);
#pragma unroll
        for (int j = 0; j < 4; ++j) {
            bf16x8 bh0 = *(const bf16x8*)&KHs[j * 16 + lr][quad * 8];
            bf16x8 bh1 = *(const bf16x8*)&KHs[j * 16 + lr][32 + quad * 8];
            f32x4 sa = (f32x4){0.f, 0.f, 0.f, 0.f};
            sa = __builtin_amdgcn_mfma_f32_16x16x32_bf16(qh[0], bh0, sa, 0, 0, 0);
            sa = __builtin_amdgcn_mfma_f32_16x16x32_bf16(qh[1], bh1, sa, 0, 0, 0);
            const float mo = mkf[j * 16 + lr];
#pragma unroll
            for (int r = 0; r < 4; ++r)
                rs[r] += exp2f(fmaf(sa[r], s2, mo));
        }
    }

    // drain phase-1 LDS reads before reusing buffers in phase 2
    asm volatile("s_waitcnt lgkmcnt(0)" ::: "memory");
    __builtin_amdgcn_s_barrier();
    __builtin_amdgcn_sched_barrier(0);

    // phase-2 prologue prefetch (flies during the rinv reduce)
    uint4 pKH2, pKL2, pV2; int pmk2 = 0;
    {
        const size_t kb = ((size_t)(b * SEQ)) * DM + h * HD;
        const size_t vb = ((size_t)((b * NH + h) * HD)) * SEQ;
        pKH2 = *(const uint4*)&Khi[kb + (size_t)r0 * DM + c0];
        pKL2 = *(const uint4*)&Klo[kb + (size_t)r0 * DM + c0];
        pV2  = *(const uint4*)&Vg[vb + (size_t)r0 * SEQ + c0];
        if (tid < 64) pmk2 = mask[b * SEQ + tid];
    }

    float rinv[4];
#pragma unroll
    for (int r = 0; r < 4; ++r) {
        float t = rs[r];
        t += __shfl_xor(t, 1, 16);
        t += __shfl_xor(t, 2, 16);
        t += __shfl_xor(t, 4, 16);
        t += __shfl_xor(t, 8, 16);
        rinv[r] = 1.0f / fmaxf(t, 1e-30f);
    }

    f32x4 acc_o[4];
#pragma unroll
    for (int dt = 0; dt < 4; ++dt) acc_o[dt] = (f32x4){0.f, 0.f, 0.f, 0.f};

    // ---- phase 2: attn store + PV (full 6-term precision), T14 prefetch ----
    for (int kt = 0; kt < SEQ / 64; ++kt) {
        const int kk = kt * 64;
        asm volatile("s_waitcnt lgkmcnt(0)" ::: "memory");
        __builtin_amdgcn_s_barrier();
        __builtin_amdgcn_sched_barrier(0);
        *(uint4*)&KHs[r0][c0] = pKH2;
        *(uint4*)&KLs[r0][c0] = pKL2;
        *(uint4*)&Vs[r0][c0]  = pV2;
        if (tid < 64) mkf[tid] = pmk2 ? c2 : -3.0e38f;
        if (kt + 1 < SEQ / 64) {
            const int kk1 = (kt + 1) * 64;
            const size_t kb = ((size_t)(b * SEQ + kk1)) * DM + h * HD;
            const size_t vb = ((size_t)((b * NH + h) * HD)) * SEQ + kk1;
            pKH2 = *(const uint4*)&Khi[kb + (size_t)r0 * DM + c0];
            pKL2 = *(const uint4*)&Klo[kb + (size_t)r0 * DM + c0];
            pV2  = *(const uint4*)&Vg[vb + (size_t)r0 * SEQ + c0];
            if (tid < 64) pmk2 = mask[b * SEQ + kk1 + tid];
        }
        asm volatile("s_waitcnt lgkmcnt(0)" ::: "memory");
        __builtin_amdgcn_s_barrier();
        __builtin_amdgcn_sched_barrier(0);
#pragma unroll
        for (int j = 0; j < 4; ++j) {
            bf16x8 bh0 = *(const bf16x8*)&KHs[j * 16 + lr][quad * 8];
            bf16x8 bh1 = *(const bf16x8*)&KHs[j * 16 + lr][32 + quad * 8];
            bf16x8 bl0 = *(const bf16x8*)&KLs[j * 16 + lr][quad * 8];
            bf16x8 bl1 = *(const bf16x8*)&KLs[j * 16 + lr][32 + quad * 8];
            f32x4 sa = (f32x4){0.f, 0.f, 0.f, 0.f};
            sa = __builtin_amdgcn_mfma_f32_16x16x32_bf16(qh[0], bh0, sa, 0, 0, 0);
            sa = __builtin_amdgcn_mfma_f32_16x16x32_bf16(ql[0], bh0, sa, 0, 0, 0);
            sa = __builtin_amdgcn_mfma_f32_16x16x32_bf16(qh[0], bl0, sa, 0, 0, 0);
            sa = __builtin_amdgcn_mfma_f32_16x16x32_bf16(qh[1], bh1, sa, 0, 0, 0);
            sa = __builtin_amdgcn_mfma_f32_16x16x32_bf16(ql[1], bh1, sa, 0, 0, 0);
            sa = __builtin_amdgcn_mfma_f32_16x16x32_bf16(qh[1], bl1, sa, 0, 0, 0);
            const float mo = mkf[j * 16 + lr];
#pragma unroll
            for (int r = 0; r < 4; ++r) {
                const float pn = exp2f(fmaf(sa[r], s2, mo)) * rinv[r];
                const int qrow = q0 + w * 16 + quad * 4 + r;
                attn[((size_t)(b * NH + h) * SEQ + qrow) * SEQ + kk + j * 16 + lr] = pn;
                Ps[w * 16 + quad * 4 + r][j * 16 + lr] = (short)f2bf(pn);
            }
        }
        // PV: wave reads only its own Ps rows (written above) -> no barrier
        bf16x8 pa0 = *(const bf16x8*)&Ps[w * 16 + lr][quad * 8];
        bf16x8 pa1 = *(const bf16x8*)&Ps[w * 16 + lr][32 + quad * 8];
#pragma unroll
        for (int dt = 0; dt < 4; ++dt) {
            bf16x8 bv0 = *(const bf16x8*)&Vs[dt * 16 + lr][quad * 8];
            bf16x8 bv1 = *(const bf16x8*)&Vs[dt * 16 + lr][32 + quad * 8];
            acc_o[dt] = __builtin_amdgcn_mfma_f32_16x16x32_bf16(pa0, bv0, acc_o[dt], 0, 0, 0);
            acc_o[dt] = __builtin_amdgcn_mfma_f32_16x16x32_bf16(pa1, bv1, acc_o[dt], 0, 0, 0);
        }
    }

    // ---- ctx out (bf16, row-major [B,S,D]) ----
#pragma unroll
    for (int dt = 0; dt < 4; ++dt)
#pragma unroll
        for (int r = 0; r < 4; ++r)
            ctxb[((size_t)(b * SEQ + q0 + w * 16 + quad * 4 + r)) * DM +
                 h * HD + dt * 16 + lr] = (unsigned short)f2bf(acc_o[dt][r]);
}

// ---------------------------------------------------------------------------
extern "C" void kernel_launch(void* const* d_in, const int* in_sizes, int n_in,
                              void* d_out, int out_size, void* d_ws, size_t ws_size,
                              hipStream_t stream)
{
    const float* query = (const float*)d_in[0];
    const float* key   = (const float*)d_in[1];
    const float* value = (const float*)d_in[2];
    const int*   mask  = (const int*)d_in[3];
    const float* Wq = (const float*)d_in[4];
    const float* bq = (const float*)d_in[5];
    const float* Wk = (const float*)d_in[6];
    const float* bk = (const float*)d_in[7];
    const float* Wv = (const float*)d_in[8];
    const float* bv = (const float*)d_in[9];
    const float* Wo = (const float*)d_in[10];
    const float* bo = (const float*)d_in[11];
    const float* scale = (const float*)d_in[12];

    float* out_ctx  = (float*)d_out;                 // [B,S,DM]
    float* out_attn = out_ctx + (size_t)MR * DM;     // [B,NH,S,S]

    const size_t WSZ = (size_t)DM * DM;   // 1M elems
    const size_t TSZ = (size_t)MR * DM;   // 4M elems
    unsigned short* p = (unsigned short*)d_ws;
    unsigned short* Wq_hi = p; p += WSZ;
    unsigned short* Wq_lo = p; p += WSZ;
    unsigned short* Wk_hi = p; p += WSZ;
    unsigned short* Wk_lo = p; p += WSZ;
    unsigned short* Wv_b  = p; p += WSZ;
    unsigned short* Wo_b  = p; p += WSZ;
    unsigned short* Qn_hi = p; p += TSZ;
    unsigned short* Qn_lo = p; p += TSZ;
    unsigned short* Kn_hi = p; p += TSZ;
    unsigned short* Kn_lo = p; p += TSZ;
    unsigned short* Vg    = p; p += TSZ;
    // ctxb aliases Wq_hi..Wk_lo (4*WSZ == TSZ elems), dead after Q/K proj
    unsigned short* ctxb  = Wq_hi;
    // Activation pre-split scratch lives in the (not yet written) attn output
    unsigned short* Ahi = (unsigned short*)out_attn;
    unsigned short* Alo = Ahi + TSZ;

    convert_split <<<1024, 256, 0, stream>>>(Wq, Wq_hi, Wq_lo, 262144);
    convert_split <<<1024, 256, 0, stream>>>(Wk, Wk_hi, Wk_lo, 262144);
    convert_single<<<1024, 256, 0, stream>>>(Wv, Wv_b, 262144);
    convert_single<<<1024, 256, 0, stream>>>(Wo, Wo_b, 262144);

    dim3 gg(MR / 64, DM / 128);

    convert_split <<<4096, 256, 0, stream>>>(query, Ahi, Alo, (int)(TSZ / 4));
    proj_gemm<0><<<gg, 256, 0, stream>>>(Ahi, Alo, Wq_hi, Wq_lo, bq, Qn_hi, Qn_lo);
    convert_split <<<4096, 256, 0, stream>>>(key, Ahi, Alo, (int)(TSZ / 4));
    proj_gemm<0><<<gg, 256, 0, stream>>>(Ahi, Alo, Wk_hi, Wk_lo, bk, Kn_hi, Kn_lo);
    convert_single<<<4096, 256, 0, stream>>>(value, Ahi, (int)(TSZ / 4));
    proj_gemm<1><<<gg, 256, 0, stream>>>(Ahi, nullptr, Wv_b, nullptr, bv, Vg, nullptr);

    attn_fused<<<dim3(SEQ / 128 * NH * BATCH), 512, 0, stream>>>(
        Qn_hi, Qn_lo, Kn_hi, Kn_lo, Vg, mask, scale, out_attn, ctxb);

    proj_gemm<2><<<gg, 256, 0, stream>>>(ctxb, nullptr, Wo_b, nullptr, bo, out_ctx, nullptr);
}